// Round 4
// baseline (441.056 us; speedup 1.0000x reference)
//
#include <hip/hip_runtime.h>
#include <hip/hip_bf16.h>

using bf16x8 = __attribute__((ext_vector_type(8))) short;
using f32x16 = __attribute__((ext_vector_type(16))) float;

constexpr int BATCH = 32, CIN = 64, H = 128, W = 128, COUT = 128, OH = 126, OW = 126;
constexpr int OHT = 2, IHT = 4;          // full-width tile: 2 output rows, 4 input rows
constexpr int NPIX = IHT * W;            // 512 pixels (power of 2)
constexpr int XUNITS = (CIN / 8) * NPIX; // 4096 16B-units = 64 KiB
constexpr int NTH = 1024;
constexpr int NFRAG = 9 * 4 * 4 * 64;    // kk*kq*m*lane

// ---- weight transform: fp32 OIHW -> bf16 MFMA-A fragments [kk][kq][m][lane][8]
// A-frag (32x32x16): row(cout within m-group) = lane&31, k = (lane>>5)*8 + j
__global__ void wt_transform(const float* __restrict__ w, ushort* __restrict__ wtf) {
    int t = blockIdx.x * 256 + threadIdx.x;
    if (t >= NFRAG * 8) return;
    int j  = t & 7;
    int l  = (t >> 3) & 63;
    int m  = (t >> 9) & 3;
    int kq = (t >> 11) & 3;
    int kk = t >> 13;
    int co = m * 32 + (l & 31);
    int ci = kq * 16 + (l >> 5) * 8 + j;
    float v = w[(size_t)(co * CIN + ci) * 9 + kk];
    __hip_bfloat16 h = __float2bfloat16(v);
    wtf[t] = *reinterpret_cast<ushort*>(&h);
}

__global__ __launch_bounds__(NTH, 2) void conv_mfma(
    const float* __restrict__ x, const ushort* __restrict__ wtf,
    const float* __restrict__ bias, const float* __restrict__ mult,
    float* __restrict__ out)
{
    __shared__ __align__(16) ushort xs[XUNITS * 8];   // 65536 B, [c_unit][pix], linear

    const int tid = threadIdx.x;
    const int b   = blockIdx.y;
    const int oh0 = blockIdx.x * OHT;                 // 0..124, ih 0..3 never clamps
    const int wave = tid >> 6, lane = tid & 63;
    const int m = wave >> 2;            // cout group (32 couts)
    const int r = (wave >> 1) & 1;      // output row within tile
    const int c = wave & 1;             // 64-px column half
    const int l31 = lane & 31, l5 = lane >> 5;

    // ---- stage x tile: fp32 NCHW -> bf16 [c_unit][pix]; all shifts, no clamps.
    // Writes: consecutive lanes -> consecutive 16B units -> conflict-free.
    #pragma unroll
    for (int i = 0; i < XUNITS / NTH; ++i) {
        int j  = i * NTH + tid;
        int c8 = j >> 9, p = j & 511;
        int ih = p >> 7, iw = p & 127;
        const float* xp = x + (size_t)(b * CIN + c8 * 8) * (H * W) + (oh0 + ih) * W + iw;
        bf16x8 v;
        #pragma unroll
        for (int q = 0; q < 8; ++q) {
            __hip_bfloat16 h = __float2bfloat16(xp[q * (H * W)]);
            v[q] = (short)*reinterpret_cast<ushort*>(&h);
        }
        *reinterpret_cast<bf16x8*>(&xs[(c8 * NPIX + p) * 8]) = v;
    }
    __syncthreads();                                  // the ONLY barrier

    f32x16 acc0, acc1;
    #pragma unroll
    for (int i = 0; i < 16; ++i) { acc0[i] = 0.f; acc1[i] = 0.f; }

    const bf16x8* wf = reinterpret_cast<const bf16x8*>(wtf);
    // per-lane LDS base; l5 folded in so every ds_read offset is compile-time
    const ushort* bb = &xs[((l5 * NPIX) + (r * W + c * 64 + l31)) * 8];

    #pragma unroll
    for (int kk = 0; kk < 9; ++kk) {
        const int kh = kk / 3, kw = kk - kh * 3;      // compile-time after unroll
        #pragma unroll
        for (int kq = 0; kq < 4; ++kq) {
            bf16x8 a = wf[((kk * 4 + kq) * 4 + m) * 64 + lane];
            const ushort* bp = bb + (size_t)(kq * 2 * NPIX + kh * W + kw) * 8;
            bf16x8 b0 = *reinterpret_cast<const bf16x8*>(bp);
            bf16x8 b1 = *reinterpret_cast<const bf16x8*>(bp + 32 * 8);
            acc0 = __builtin_amdgcn_mfma_f32_32x32x16_bf16(a, b0, acc0, 0, 0, 0);
            acc1 = __builtin_amdgcn_mfma_f32_32x32x16_bf16(a, b1, acc1, 0, 0, 0);
        }
    }

    // ---- epilogue: bias -> mult -> leaky(fmax) -> gelu via sigmoid(2z)
    const int oh  = oh0 + r;
    const int owb = c * 64 + l31;        // t0 col, always < 126
    const bool m1 = owb + 32 < OW;       // t1 mask (only c=1 lanes 30,31 fail)
    #pragma unroll
    for (int i = 0; i < 16; ++i) {
        const int co = m * 32 + (i & 3) + 8 * (i >> 2) + 4 * l5;   // C/D row map
        const float bi = bias[co];
        const float mu = mult[co];
        float* po = out + ((size_t)(b * COUT + co) * OH + oh) * OW;
        {
            float y = (acc0[i] + bi) * mu;
            y = fmaxf(y, 0.01f * y);                  // leaky relu
            float u = y * __builtin_fmaf(0.044715f, y * y, 1.0f);
            float e = __expf(-1.5957691216057308f * u);   // exp(-2z)
            po[owb] = y * __builtin_amdgcn_rcpf(1.0f + e);
        }
        if (m1) {
            float y = (acc1[i] + bi) * mu;
            y = fmaxf(y, 0.01f * y);
            float u = y * __builtin_fmaf(0.044715f, y * y, 1.0f);
            float e = __expf(-1.5957691216057308f * u);
            po[owb + 32] = y * __builtin_amdgcn_rcpf(1.0f + e);
        }
    }
}

extern "C" void kernel_launch(void* const* d_in, const int* in_sizes, int n_in,
                              void* d_out, int out_size, void* d_ws, size_t ws_size,
                              hipStream_t stream)
{
    const float* x    = (const float*)d_in[0];
    const float* w    = (const float*)d_in[1];
    const float* bias = (const float*)d_in[2];
    const float* mult = (const float*)d_in[3];
    float* out = (float*)d_out;
    ushort* wtf = (ushort*)d_ws;   // 147456 B

    hipLaunchKernelGGL(wt_transform, dim3((NFRAG * 8 + 255) / 256), dim3(256), 0, stream, w, wtf);
    dim3 grid(OH / OHT, BATCH);    // (63, 32) = 2016 blocks, exact cover
    hipLaunchKernelGGL(conv_mfma, grid, dim3(NTH), 0, stream, x, wtf, bias, mult, out);
}